// Round 6
// baseline (906.791 us; speedup 1.0000x reference)
//
#include <hip/hip_runtime.h>
#include <hip/hip_fp16.h>

// ---------------- constants ----------------
#define HID 128
#define N_LAYERS 4
#define IN_DIM 32
#define N_CLASSES 16

typedef _Float16 f16x8 __attribute__((ext_vector_type(8)));
typedef float f32x2 __attribute__((ext_vector_type(2)));
typedef __attribute__((ext_vector_type(4))) float f32x4;
typedef unsigned int uint_t;

#if defined(__has_builtin)
#if __has_builtin(__builtin_amdgcn_cvt_pk_f32_fp8)
#define HAVE_CVT_FP8 1
#endif
#if __has_builtin(__builtin_amdgcn_cvt_pk_fp8_f32)
#define HAVE_ENC_FP8 1
#endif
#endif

__device__ __forceinline__ unsigned short f2bf(float f) {
    unsigned int u = __float_as_uint(f);
    return (unsigned short)((u + 0x7FFFu + ((u >> 16) & 1u)) >> 16);  // RNE
}
__device__ __forceinline__ float2 up16(uint_t u) {
    __half2 h = *(__half2*)&u;
    return __half22float2(h);
}

// ---- fp8 e4m3fn (OCP) encode/decode (manual fallbacks) ----
__device__ __forceinline__ unsigned char f2e4m3(float f) {
    unsigned int u = __float_as_uint(f);
    unsigned char s = (unsigned char)((u >> 24) & 0x80u);
    unsigned int a = u & 0x7FFFFFFFu;
    if (a >= 0x43E00000u) return s | 0x7Eu;
    int exp = (int)(a >> 23) - 127;
    if (exp < -6) {
        int m = (int)rintf(__uint_as_float(a) * 512.f);
        return s | (unsigned char)m;
    }
    unsigned int lsb = (a >> 20) & 1u;
    a += 0x7FFFFu + lsb;
    int e8 = ((int)(a >> 23) - 127) + 7;
    unsigned int m8 = (a >> 20) & 7u;
    return s | (unsigned char)((e8 << 3) | (int)m8);
}
__device__ __forceinline__ float e4m32f(unsigned int b) {
    unsigned int s = (b & 0x80u) << 24;
    unsigned int E = (b >> 3) & 15u, m = b & 7u;
    if (E == 0) {
        float v = (float)m * 0.001953125f;
        return __uint_as_float(__float_as_uint(v) | s);
    }
    return __uint_as_float(s | ((E + 120u) << 23) | (m << 20));
}
__device__ __forceinline__ unsigned char enc8(float v) {
#ifdef HAVE_ENC_FP8
    int r = __builtin_amdgcn_cvt_pk_fp8_f32(v, v, 0, false);
    return (unsigned char)(r & 0xFF);
#else
    return f2e4m3(v);
#endif
}
__device__ __forceinline__ void dec8v(uint_t u, f32x2* o) {  // 4 fp8 -> 2x f32x2
#ifdef HAVE_CVT_FP8
    o[0] = __builtin_amdgcn_cvt_pk_f32_fp8(u, false);
    o[1] = __builtin_amdgcn_cvt_pk_f32_fp8(u, true);
#else
    o[0] = (f32x2){e4m32f(u & 255u), e4m32f((u >> 8) & 255u)};
    o[1] = (f32x2){e4m32f((u >> 16) & 255u), e4m32f(u >> 24)};
#endif
}

// fragment-layout byte offset within a wave's 16x128 A-plane (or a half-tile's 32x128):
// element (row,k): (k>>5)*1024 + ((k>>3)&3)*256 + row*16 + (k&7)*2
__device__ __forceinline__ int frag_off(int row, int c) {
    return ((c >> 5) << 10) + (((c >> 3) & 3) << 8) + (row << 4) + ((c & 7) << 1);
}

// ---------------- dtype detect ----------------
__global__ void detect_kernel(const unsigned int* __restrict__ ln1g, int* __restrict__ flag) {
    if (threadIdx.x == 0 && blockIdx.x == 0)
        *flag = (ln1g[0] == 0x3F800000u) ? 0 : 1;
}

// ---------------- small-param conversion (bf16-or-fp32 -> fp32) ----------------
#define NSM 11
struct SArgs {
    const void* src[NSM];
    float*      dst[NSM];
    int         cnt[NSM];
};

__global__ void conv_kernel(SArgs args, const int* __restrict__ flag) {
    int p = blockIdx.y;
    int n = args.cnt[p];
    int base = (blockIdx.x * 256 + threadIdx.x) * 4;
    if (base >= n) return;
    float* dst = args.dst[p];
    if (*flag) {
        const unsigned short* s = (const unsigned short*)args.src[p];
        #pragma unroll
        for (int j = 0; j < 4; ++j)
            dst[base + j] = __uint_as_float(((unsigned int)s[base + j]) << 16);
    } else {
        const float* s = (const float*)args.src[p];
        *(float4*)&dst[base] = *(const float4*)&s[base];
    }
}

// ---------------- weight conversion: fp16 + layout ----------------
// mode 0: plain transpose dst[m*K+k]
// mode 1: K=128 tiled half-tiles (32 cols x 128 k, fragment-ordered)
// mode 2: K=256 (W2) tiled: htIdx = (k>>7)*4 + (m>>5)
#define NW 27
struct WArgs {
    const void* src[NW];
    int         soff[NW];
    _Float16*   dst[NW];
    int         K[NW];
    int         M[NW];
    int         mode[NW];
};

__global__ void wconv_kernel(WArgs a, const int* __restrict__ flag) {
    int p = blockIdx.y;
    int K = a.K[p], M = a.M[p], mode = a.mode[p];
    int idx = blockIdx.x * 256 + threadIdx.x;
    if (idx >= K * M) return;
    int k = idx / M, m = idx % M;
    float v;
    if (*flag)
        v = __uint_as_float(((unsigned int)((const unsigned short*)a.src[p])[a.soff[p] + idx]) << 16);
    else
        v = ((const float*)a.src[p])[a.soff[p] + idx];
    size_t off;
    if (mode == 0) {
        off = (size_t)m * K + k;
    } else {
        int ht, k2;
        if (mode == 1) { ht = m >> 5; k2 = k; }
        else           { ht = ((k >> 7) << 2) + (m >> 5); k2 = k & 127; }
        // frag = (kk*2 + i2)*64 + quad*16 + lc ; off = ht*4096 + frag*8 + e
        int frag = (((k2 >> 5) * 2 + ((m >> 4) & 1)) << 6) + (((k2 >> 3) & 3) << 4) + (m & 15);
        off = (size_t)ht * 4096 + frag * 8 + (k & 7);
    }
    a.dst[p][off] = (_Float16)v;
}

// ---------------- CSR from sorted edge_dst ----------------
__global__ void csr_kernel(const int* __restrict__ dst, int* __restrict__ row_start,
                           int N, int E) {
    int n = blockIdx.x * 256 + threadIdx.x;
    if (n > N) return;
    int lo = 0, hi = E;
    while (lo < hi) {
        int mid = (lo + hi) >> 1;
        if (dst[mid] < n) lo = mid + 1; else hi = mid;
    }
    row_start[n] = lo;
}

// ---------------- embedding gather (h fp16) ----------------
__global__ void embed_kernel(const int* __restrict__ feat, const float* __restrict__ emb,
                             _Float16* __restrict__ h, int N) {
    int idx = blockIdx.x * 256 + threadIdx.x;   // 8 fp16 per thread
    if (idx >= N * 16) return;
    int n  = idx >> 4;
    int c8 = idx & 15;
    int f = feat[n];
    const float* s = &emb[(size_t)f * HID + c8 * 8];
    float4 a = *(const float4*)s;
    float4 b = *(const float4*)(s + 4);
    f16x8 o;
    o[0] = (_Float16)a.x; o[1] = (_Float16)a.y; o[2] = (_Float16)a.z; o[3] = (_Float16)a.w;
    o[4] = (_Float16)b.x; o[5] = (_Float16)b.y; o[6] = (_Float16)b.z; o[7] = (_Float16)b.w;
    *(f16x8*)&h[(size_t)n * HID + c8 * 8] = o;
}

// ---------------- layer-0 QKV (tiled-B, frag-A) ----------------
__launch_bounds__(256)
__global__ void mfma_gemm_qkv(const _Float16* __restrict__ Ain,
                              const _Float16* __restrict__ Bt,
                              _Float16* __restrict__ q16, unsigned char* __restrict__ kvp8) {
    __shared__ __align__(16) char As[16384];
    __shared__ __align__(16) char Bs[49152];

    const int t    = threadIdx.x;
    const int w    = t >> 6;
    const int l    = t & 63;
    const int quad = l >> 4;
    const int lc   = l & 15;
    const int row0 = blockIdx.x * 64;
    const int mbase = blockIdx.y * 192;

    char* Aw = As + (w << 12);

    // stage A rows w*16..+15, fragment layout (coalesced global read, scatter LDS write)
    #pragma unroll
    for (int i = 0; i < 4; ++i) {
        int idx = i * 64 + l;
        int row = idx >> 4, g = idx & 15;
        uint4 v = *(const uint4*)(Ain + (size_t)(row0 + w * 16 + row) * 128 + g * 8);
        *(uint4*)(Aw + ((g >> 2) << 10) + ((g & 3) << 8) + (row << 4)) = v;
    }
    // stage B: 6 half-tiles linear copy
    {
        const uint4* Bsrc = (const uint4*)(Bt + (size_t)(mbase / 32) * 4096);
        #pragma unroll
        for (int i = 0; i < 12; ++i) {
            int idx = t + i * 256;
            *(uint4*)&Bs[idx * 16] = Bsrc[idx];
        }
    }
    __syncthreads();

    f32x4 acc[12];
    #pragma unroll
    for (int i = 0; i < 12; ++i) acc[i] = (f32x4){0.f, 0.f, 0.f, 0.f};

    #pragma unroll
    for (int kk = 0; kk < 4; ++kk) {
        f16x8 af = *(const f16x8*)(Aw + (kk << 10) + (quad << 8) + (lc << 4));
        #pragma unroll
        for (int i = 0; i < 12; ++i) {
            f16x8 bf = *(const f16x8*)(Bs + (i >> 1) * 8192 +
                                       ((kk * 2 + (i & 1)) << 10) + (quad << 8) + (lc << 4));
            acc[i] = __builtin_amdgcn_mfma_f32_16x16x32_f16(af, bf, acc[i], 0, 0, 0);
        }
    }

    #pragma unroll
    for (int r = 0; r < 4; ++r) {
        int row = row0 + w * 16 + quad * 4 + r;
        #pragma unroll
        for (int i = 0; i < 12; ++i) {
            float v = acc[i][r];
            int gc = mbase + i * 16 + lc;
            if (gc < 128)      q16[(size_t)row * 128 + gc] = (_Float16)v;
            else if (gc < 256) kvp8[(size_t)row * 256 + (gc - 128)] = enc8(v);
            else               kvp8[(size_t)row * 256 + 128 + (gc - 256)] = enc8(v);
        }
    }
}

// ---------------- FULLY-FUSED layer, BARRIER-FREE ----------------
// Every wave is an independent instruction stream (zero __syncthreads):
//  - attn phase: wave-private rows, gather from kvin (read-only).
//  - GEMM phases: A operand cached in registers (loaded once per section from the
//    wave-private LDS plane); B fragments read DIRECT from global — the fragment-ordered
//    tiled weight layout makes each (kk,i) read a contiguous 1KB block per wave
//    (coalesced, L1-shared across the block's 4 waves, L2-resident).
//  - waves that finish attn early flow straight into GEMM while slow waves still
//    gather -> wave-granular attn/GEMM overlap.
// Hazards audited: bufA/bufH wave-private; q16/kv/h rows wave-private (RMODE r0 padded
// to stride 128 so writes stay within the writing wave's own q16 rows).
// LDS 32KB, launch_bounds(256,4) -> 4 blocks/CU (16 waves) for gather latency hiding.
template<int NEXTM, bool RMODE>
__launch_bounds__(256, 4)
__global__ void layer_fused(_Float16* __restrict__ h,
                            const _Float16* __restrict__ Wo, const _Float16* __restrict__ W1,
                            const _Float16* __restrict__ W2,
                            const _Float16* __restrict__ Wn, const float* __restrict__ bn,
                            const float* __restrict__ bo,  const float* __restrict__ l1g,
                            const float* __restrict__ l1b, const float* __restrict__ b1,
                            const float* __restrict__ b2,  const float* __restrict__ l2g,
                            const float* __restrict__ l2b,
                            _Float16* __restrict__ q16,
                            const uint_t* __restrict__ kvin, unsigned char* __restrict__ kvout,
                            const int* __restrict__ esrc, const int* __restrict__ rows,
                            int N) {
    constexpr int NHT = NEXTM / 32;     // next-proj half-tiles (12 or 2)
    __shared__ __align__(16) char bufA[16384];   // attn-out -> t1 half-plane -> h_new
    __shared__ __align__(16) char bufH[16384];   // h' post-LN1 (frag layout)

    const int t = threadIdx.x, w = t >> 6, l = t & 63;
    const int quad = l >> 4, lc = l & 15;
    const int row0 = blockIdx.x * 64;
    char* Aw = bufA + (w << 12);
    char* Hw = bufH + (w << 12);

    // load the wave's A fragments (one 16x128 plane) into registers
    auto LDA = [&](const char* Ar, f16x8* afc) {
        #pragma unroll
        for (int kk = 0; kk < 4; ++kk)
            afc[kk] = *(const f16x8*)(Ar + (kk << 10) + (quad << 8) + (lc << 4));
    };
    // 2-tile MFMA vs one 32-col half-tile of B, read direct from global (tiled layout)
    auto MF2G = [&](const f16x8* afc, const _Float16* B, f32x4* ac) {
        #pragma unroll
        for (int kk = 0; kk < 4; ++kk) {
            #pragma unroll
            for (int i = 0; i < 2; ++i) {
                f16x8 bf = *(const f16x8*)((const char*)B +
                            (((kk * 2 + i) << 10) + (quad << 8) + (lc << 4)));
                ac[i] = __builtin_amdgcn_mfma_f32_16x16x32_f16(afc[kk], bf, ac[i], 0, 0, 0);
            }
        }
    };

    // ---- LN1 residual prefetch (C/D positions) ----
    _Float16 resv[4][8];
    #pragma unroll
    for (int r = 0; r < 4; ++r) {
        int row = row0 + w * 16 + quad * 4 + r;
        #pragma unroll
        for (int j = 0; j < 8; ++j)
            resv[r][j] = h[(size_t)row * 128 + j * 16 + lc];
    }

    // ---- fused edge attention -> Aw (fragment layout), wave-private rows ----
    {
        const int head = l & 7;
        const int rsub = l >> 3;              // 0..7
        #pragma unroll
        for (int task = 0; task < 2; ++task) {
            const int rr   = rsub + task * 8; // row within wave plane, 0..15
            const int node = row0 + w * 16 + rr;
            f16x8 o0, o1;
            #pragma unroll
            for (int j = 0; j < 8; ++j) { o0[j] = (_Float16)0; o1[j] = (_Float16)0; }
            if (node < N) {
                f32x2 qh[8];
                {
                    const uint4* qp = (const uint4*)(q16 + (size_t)node * HID + head * 16);
                    uint4 q0 = qp[0], q1 = qp[1];
                    uint_t qs[8] = {q0.x, q0.y, q0.z, q0.w, q1.x, q1.y, q1.z, q1.w};
                    #pragma unroll
                    for (int i = 0; i < 8; ++i) {
                        float2 f = up16(qs[i]);
                        qh[i] = (f32x2){f.x * 0.25f, f.y * 0.25f};   // fold 1/sqrt(dk)
                    }
                }
                int e0 = rows[node], e1 = rows[node + 1];
                f32x2 wv[8];
                #pragma unroll
                for (int i = 0; i < 8; ++i) wv[i] = (f32x2){0.f, 0.f};
                float z = 0.f;

                uint4 ka = {0,0,0,0}, va = {0,0,0,0}, kc = {0,0,0,0}, vc = {0,0,0,0};
                bool oka = e0 < e1, okc = e0 + 1 < e1;
                if (oka) {
                    int sa = esrc[e0];
                    int sc = okc ? esrc[e0 + 1] : sa;
                    ka = *(const uint4*)(kvin + (size_t)sa * 64 + head * 4);
                    va = *(const uint4*)(kvin + (size_t)sa * 64 + 32 + head * 4);
                    kc = *(const uint4*)(kvin + (size_t)sc * 64 + head * 4);
                    vc = *(const uint4*)(kvin + (size_t)sc * 64 + 32 + head * 4);
                }
                for (int e = e0; e < e1; e += 2) {
                    uint4 cka = ka, cva = va, ckc = kc, cvc = vc;
                    bool coka = oka, cokc = okc;
                    int en = e + 2;
                    oka = en < e1; okc = en + 1 < e1;
                    if (oka) {
                        int sa = esrc[en];
                        int sc = okc ? esrc[en + 1] : sa;
                        ka = *(const uint4*)(kvin + (size_t)sa * 64 + head * 4);
                        va = *(const uint4*)(kvin + (size_t)sa * 64 + 32 + head * 4);
                        kc = *(const uint4*)(kvin + (size_t)sc * 64 + head * 4);
                        vc = *(const uint4*)(kvin + (size_t)sc * 64 + 32 + head * 4);
                    }
                    f32x2 k2a[8], k2c[8];
                    dec8v(cka.x, k2a); dec8v(cka.y, k2a + 2); dec8v(cka.z, k2a + 4); dec8v(cka.w, k2a + 6);
                    dec8v(ckc.x, k2c); dec8v(ckc.y, k2c + 2); dec8v(ckc.z, k2c + 4); dec8v(ckc.w, k2c + 6);
                    f32x2 da2 = (f32x2){0.f, 0.f}, dc2 = (f32x2){0.f, 0.f};
                    #pragma unroll
                    for (int j = 0; j < 8; ++j) { da2 += qh[j] * k2a[j]; dc2 += qh[j] * k2c[j]; }
                    float da = da2.x + da2.y, dc = dc2.x + dc2.y;
                    float sa2 = coka ? __expf(fminf(fmaxf(da, -5.f), 5.f)) : 0.f;
                    float sc2 = cokc ? __expf(fminf(fmaxf(dc, -5.f), 5.f)) : 0.f;

                    f32x2 v2a[8], v2c[8];
                    dec8v(cva.x, v2a); dec8v(cva.y, v2a + 2); dec8v(cva.z, v2a + 4); dec8v(cva.w, v2a + 6);
                    dec8v(cvc.x, v2c); dec8v(cvc.y, v2c + 2); dec8v(cvc.z, v2c + 4); dec8v(cvc.w, v2c + 6);
                    f32x2 pa = (f32x2){sa2, sa2}, pc = (f32x2){sc2, sc2};
                    #pragma unroll
                    for (int j = 0; j < 8; ++j) { wv[j] += pa * v2a[j]; wv[j] += pc * v2c[j]; }
                    z += sa2 + sc2;
                }
                float inv = 1.f / (z + 1e-6f);
                #pragma unroll
                for (int i = 0; i < 4; ++i) {
                    o0[2*i]   = (_Float16)(wv[i].x * inv);
                    o0[2*i+1] = (_Float16)(wv[i].y * inv);
                    o1[2*i]   = (_Float16)(wv[4+i].x * inv);
                    o1[2*i+1] = (_Float16)(wv[4+i].y * inv);
                }
            }
            // write 16 outputs into Aw fragment layout: two aligned 16B spans
            *(f16x8*)(Aw + frag_off(rr, head * 16))     = o0;
            *(f16x8*)(Aw + frag_off(rr, head * 16 + 8)) = o1;
        }
    }

    // ---- O-proj: 4 half-tile chunks, A cached in regs, B direct from global ----
    f16x8 afc[4];
    LDA(Aw, afc);
    f32x4 acc[8];
    #pragma unroll
    for (int i = 0; i < 8; ++i) acc[i] = (f32x4){0.f, 0.f, 0.f, 0.f};
    #pragma unroll
    for (int c = 0; c < 4; ++c)
        MF2G(afc, Wo + (size_t)c * 4096, acc + c * 2);

    // ---- +bo, +res, LN1 -> Hw ----
    {
        float gv[8], bv[8], bb8[8];
        #pragma unroll
        for (int j = 0; j < 8; ++j) {
            int col = j * 16 + lc;
            gv[j] = l1g[col]; bv[j] = l1b[col]; bb8[j] = bo[col];
        }
        #pragma unroll
        for (int r = 0; r < 4; ++r) {
            float v[8];
            float s = 0.f, ss = 0.f;
            #pragma unroll
            for (int j = 0; j < 8; ++j) {
                v[j] = acc[j][r] + bb8[j] + (float)resv[r][j];
                s += v[j]; ss += v[j] * v[j];
            }
            #pragma unroll
            for (int m = 1; m <= 8; m <<= 1) { s += __shfl_xor(s, m); ss += __shfl_xor(ss, m); }
            float mu   = s * (1.f / 128.f);
            float rstd = rsqrtf(ss * (1.f / 128.f) - mu * mu + 1e-5f);
            #pragma unroll
            for (int j = 0; j < 8; ++j) {
                float o = (v[j] - mu) * rstd * gv[j] + bv[j];
                *(_Float16*)(Hw + frag_off(quad * 4 + r, j * 16 + lc)) = (_Float16)o;
            }
        }
    }

    // ---- FFN1/FFN2 per K-half; A(FFN1)=Hw cached once, A(FFN2)=Aw cached per half ----
    f32x4 acc3[8];
    #pragma unroll
    for (int i = 0; i < 8; ++i) acc3[i] = (f32x4){0.f, 0.f, 0.f, 0.f};
    f16x8 afh[4];
    LDA(Hw, afh);
    #pragma unroll
    for (int hh = 0; hh < 2; ++hh) {
        // FFN1: 4 half-tiles -> relu -> Aw (k = j*32 + i2*16 + lc)
        #pragma unroll
        for (int j = 0; j < 4; ++j) {
            f32x4 a2[2];
            a2[0] = (f32x4){0.f, 0.f, 0.f, 0.f};
            a2[1] = (f32x4){0.f, 0.f, 0.f, 0.f};
            MF2G(afh, W1 + (size_t)(hh * 4 + j) * 4096, a2);
            #pragma unroll
            for (int r = 0; r < 4; ++r) {
                #pragma unroll
                for (int i2 = 0; i2 < 2; ++i2) {
                    float v = a2[i2][r] + b1[(hh * 4 + j) * 32 + i2 * 16 + lc];
                    v = fmaxf(v, 0.f);
                    *(_Float16*)(Aw + frag_off(quad * 4 + r, j * 32 + i2 * 16 + lc)) = (_Float16)v;
                }
            }
        }
        // FFN2: 4 output-col half-tiles, accumulate across K-halves
        f16x8 aft[4];
        LDA(Aw, aft);
        #pragma unroll
        for (int j = 0; j < 4; ++j)
            MF2G(aft, W2 + (size_t)(hh * 4 + j) * 4096, acc3 + j * 2);
    }

    // ---- +b2, +res(Hw), LN2 -> h global AND Aw ----
    {
        float gv[8], bv[8], bb8[8];
        #pragma unroll
        for (int j = 0; j < 8; ++j) {
            int col = j * 16 + lc;
            gv[j] = l2g[col]; bv[j] = l2b[col]; bb8[j] = b2[col];
        }
        #pragma unroll
        for (int r = 0; r < 4; ++r) {
            int row = row0 + w * 16 + quad * 4 + r;
            float v[8];
            float s = 0.f, ss = 0.f;
            #pragma unroll
            for (int j = 0; j < 8; ++j) {
                float res = (float)*(const _Float16*)(Hw + frag_off(quad * 4 + r, j * 16 + lc));
                v[j] = acc3[j][r] + bb8[j] + res;
                s += v[j]; ss += v[j] * v[j];
            }
            #pragma unroll
            for (int m = 1; m <= 8; m <<= 1) { s += __shfl_xor(s, m); ss += __shfl_xor(ss, m); }
            float mu   = s * (1.f / 128.f);
            float rstd = rsqrtf(ss * (1.f / 128.f) - mu * mu + 1e-5f);
            #pragma unroll
            for (int j = 0; j < 8; ++j) {
                float o = (v[j] - mu) * rstd * gv[j] + bv[j];
                h[(size_t)row * 128 + j * 16 + lc] = (_Float16)o;
                *(_Float16*)(Aw + frag_off(quad * 4 + r, j * 16 + lc)) = (_Float16)o;
            }
        }
    }

    // ---- next-stage projection from Aw (A cached once), NHT half-tile chunks ----
    LDA(Aw, afc);
    #pragma unroll
    for (int c = 0; c < NHT; ++c) {
        f32x4 a4[2];
        a4[0] = (f32x4){0.f, 0.f, 0.f, 0.f};
        a4[1] = (f32x4){0.f, 0.f, 0.f, 0.f};
        MF2G(afc, Wn + (size_t)c * 4096, a4);
        #pragma unroll
        for (int r = 0; r < 4; ++r) {
            int row = row0 + w * 16 + quad * 4 + r;
            #pragma unroll
            for (int i2 = 0; i2 < 2; ++i2) {
                int gc = c * 32 + i2 * 16 + lc;
                float v = a4[i2][r];
                if (RMODE) {
                    v += bn[gc];
                    v = fmaxf(v, 0.f);
                    q16[(size_t)row * 128 + gc] = (_Float16)v;   // r0 padded to stride 128
                } else {
                    if (gc < 128)      q16[(size_t)row * 128 + gc] = (_Float16)v;
                    else if (gc < 256) kvout[(size_t)row * 256 + (gc - 128)] = enc8(v);
                    else               kvout[(size_t)row * 256 + 128 + (gc - 256)] = enc8(v);
                }
            }
        }
    }
}

// ---------------- fused readout: r0[N,64 @stride128] -> relu@mW1 -> @mW2 -> d_out ------
__launch_bounds__(256)
__global__ void readout_tail(const _Float16* __restrict__ r0,
                             const _Float16* __restrict__ w1t, const float* __restrict__ b1_,
                             const _Float16* __restrict__ w2t, const float* __restrict__ b2_,
                             void* __restrict__ outp, const int* __restrict__ flag, int N) {
    constexpr int SA = 144;   // 64*2+16
    constexpr int SR = 80;    // 32*2+16
    __shared__ __align__(16) char bufA[64 * SA];
    __shared__ __align__(16) char bufR[64 * SR];

    const int t    = threadIdx.x;
    const int w    = t >> 6;
    const int l    = t & 63;
    const int quad = l >> 4;
    const int lc   = l & 15;
    const int row0 = blockIdx.x * 64;

    #pragma unroll
    for (int i = 0; i < 2; ++i) {
        int idx = t + i * 256;
        int r = idx >> 3, u = idx & 7;
        *(uint4*)&bufA[r * SA + u * 16] = *(const uint4*)(r0 + (size_t)(row0 + r) * 128 + u * 8);
    }
    __syncthreads();

    f32x4 acc[2];
    acc[0] = (f32x4){0.f, 0.f, 0.f, 0.f};
    acc[1] = (f32x4){0.f, 0.f, 0.f, 0.f};
    #pragma unroll
    for (int kk = 0; kk < 2; ++kk) {
        f16x8 af = *(const f16x8*)&bufA[(w * 16 + lc) * SA + kk * 64 + quad * 16];
        #pragma unroll
        for (int i = 0; i < 2; ++i) {
            f16x8 bf = *(const f16x8*)(w1t + (size_t)(i * 16 + lc) * 64 + kk * 32 + quad * 8);
            acc[i] = __builtin_amdgcn_mfma_f32_16x16x32_f16(af, bf, acc[i], 0, 0, 0);
        }
    }
    #pragma unroll
    for (int r = 0; r < 4; ++r) {
        int lrow = (w * 16 + quad * 4 + r) * SR;
        #pragma unroll
        for (int i = 0; i < 2; ++i) {
            float v = acc[i][r] + b1_[i * 16 + lc];
            v = fmaxf(v, 0.f);
            *(_Float16*)&bufR[lrow + (i * 16 + lc) * 2] = (_Float16)v;
        }
    }
    __syncthreads();
    f32x4 a2 = (f32x4){0.f, 0.f, 0.f, 0.f};
    {
        f16x8 af = *(const f16x8*)&bufR[(w * 16 + lc) * SR + quad * 16];
        f16x8 bf = *(const f16x8*)(w2t + (size_t)lc * 32 + quad * 8);
        a2 = __builtin_amdgcn_mfma_f32_16x16x32_f16(af, bf, a2, 0, 0, 0);
    }
    #pragma unroll
    for (int r = 0; r < 4; ++r) {
        int row = row0 + w * 16 + quad * 4 + r;
        if (row < N) {
            float v = a2[r] + b2_[lc];
            size_t o = (size_t)row * 16 + lc;
            if (*flag) ((unsigned short*)outp)[o] = f2bf(v);
            else       ((float*)outp)[o] = v;
        }
    }
}

// ---------------- host launch ----------------
extern "C" void kernel_launch(void* const* d_in, const int* in_sizes, int n_in,
                              void* d_out, int out_size, void* d_ws, size_t ws_size,
                              hipStream_t stream) {
    const int N  = in_sizes[0];
    const int E  = in_sizes[1];
    const int RB = (N + 63) / 64;
    const size_t NP = (size_t)RB * 64;       // padded row count

    const int* d_feat = (const int*)d_in[0];
    const int* d_esrc = (const int*)d_in[1];
    const int* d_edst = (const int*)d_in[2];

    char* base = (char*)d_ws;
    size_t cur = 0;
    auto alloc = [&](size_t bytes) -> char* {
        cur = (cur + 255) & ~(size_t)255;
        char* p = base + cur;
        cur += bytes;
        return p;
    };
    int* d_flag = (int*)alloc(4);
    int* d_rows = (int*)alloc((size_t)(N + 1) * 4);

    // fp32 small params
    float* p_emb = (float*)alloc(IN_DIM * HID * 4);
    float* p_bo  = (float*)alloc(N_LAYERS * HID * 4);
    float* p_l1g = (float*)alloc(N_LAYERS * HID * 4);
    float* p_l1b = (float*)alloc(N_LAYERS * HID * 4);
    float* p_b1  = (float*)alloc(N_LAYERS * 2 * HID * 4);
    float* p_b2  = (float*)alloc(N_LAYERS * HID * 4);
    float* p_l2g = (float*)alloc(N_LAYERS * HID * 4);
    float* p_l2b = (float*)alloc(N_LAYERS * HID * 4);
    float* p_mb0 = (float*)alloc(64 * 4);
    float* p_mb1 = (float*)alloc(32 * 4);
    float* p_mb2 = (float*)alloc(16 * 4);

    // fp16 weights (tiled except mw1/mw2)
    _Float16* wqkv_t = (_Float16*)alloc((size_t)N_LAYERS * 384 * 128 * 2);
    _Float16* wo_t   = (_Float16*)alloc((size_t)N_LAYERS * 128 * 128 * 2);
    _Float16* w1_t   = (_Float16*)alloc((size_t)N_LAYERS * 256 * 128 * 2);
    _Float16* w2_t   = (_Float16*)alloc((size_t)N_LAYERS * 128 * 256 * 2);
    _Float16* mw0_t  = (_Float16*)alloc(64 * 128 * 2);
    _Float16* mw1_t  = (_Float16*)alloc(32 * 64 * 2);
    _Float16* mw2_t  = (_Float16*)alloc(16 * 32 * 2);

    // activations (padded to NP rows)
    _Float16*      buf_h = (_Float16*)alloc(NP * HID * 2);
    _Float16*      q16   = (_Float16*)alloc(NP * HID * 2);   // q / r0
    unsigned char* kv0   = (unsigned char*)alloc(NP * 256);  // fp8 k|v ping
    unsigned char* kv1   = (unsigned char*)alloc(NP * 256);  // fp8 k|v pong

    // ---- 0) dtype detect ----
    detect_kernel<<<1, 64, 0, stream>>>((const unsigned int*)d_in[9], d_flag);

    // ---- 1) small params -> fp32 ----
    {
        SArgs sa;
        const int sidx[NSM] = {3, 8, 9, 10, 12, 14, 15, 16, 18, 20, 22};
        float*    sdst[NSM] = {p_emb, p_bo, p_l1g, p_l1b, p_b1, p_b2, p_l2g, p_l2b, p_mb0, p_mb1, p_mb2};
        const int scnt[NSM] = {IN_DIM*HID, N_LAYERS*HID, N_LAYERS*HID, N_LAYERS*HID,
                               N_LAYERS*2*HID, N_LAYERS*HID, N_LAYERS*HID, N_LAYERS*HID, 64, 32, 16};
        for (int i = 0; i < NSM; ++i) { sa.src[i] = d_in[sidx[i]]; sa.dst[i] = sdst[i]; sa.cnt[i] = scnt[i]; }
        conv_kernel<<<dim3(4, NSM), 256, 0, stream>>>(sa, d_flag);
    }

    // ---- 2) weights -> fp16 (tiled layouts) ----
    {
        WArgs wa;
        int wi = 0;
        auto addw = [&](int inp, int off, int Kd, int Md, _Float16* dst, int mode) {
            wa.src[wi] = d_in[inp]; wa.soff[wi] = off; wa.K[wi] = Kd; wa.M[wi] = Md;
            wa.dst[wi] = dst; wa.mode[wi] = mode; ++wi;
        };
        for (int l = 0; l < N_LAYERS; ++l) {
            addw(4,  l * 16384, 128, 128, wqkv_t + (size_t)l * 49152, 1);
            addw(5,  l * 16384, 128, 128, wqkv_t + (size_t)l * 49152 + 16384, 1);
            addw(6,  l * 16384, 128, 128, wqkv_t + (size_t)l * 49152 + 32768, 1);
            addw(7,  l * 16384, 128, 128, wo_t + (size_t)l * 16384, 1);
            addw(11, l * 32768, 128, 256, w1_t + (size_t)l * 32768, 1);
            addw(13, l * 32768, 256, 128, w2_t + (size_t)l * 32768, 2);
        }
        addw(17, 0, 128, 64, mw0_t, 1);
        addw(19, 0, 64,  32, mw1_t, 0);
        addw(21, 0, 32,  16, mw2_t, 0);
        wconv_kernel<<<dim3(128, NW), 256, 0, stream>>>(wa, d_flag);
    }

    // ---- 3) CSR + embedding ----
    csr_kernel<<<(N + 1 + 255) / 256, 256, 0, stream>>>(d_edst, d_rows, N, E);
    embed_kernel<<<((size_t)N * 16 + 255) / 256, 256, 0, stream>>>(d_feat, p_emb, buf_h, N);

    // ---- layer 0 QKV (tiled-B, 2 col-groups of 192) -> q16 + kv0 ----
    mfma_gemm_qkv<<<dim3(RB, 2), 256, 0, stream>>>(buf_h, wqkv_t, q16, kv0);

    for (int l = 0; l < N_LAYERS; ++l) {
        const _Float16* Wo = wo_t + (size_t)l * 16384;
        const _Float16* W1 = w1_t + (size_t)l * 32768;
        const _Float16* W2 = w2_t + (size_t)l * 32768;
        const float* bo  = p_bo  + (size_t)l * HID;
        const float* l1g = p_l1g + (size_t)l * HID;
        const float* l1b = p_l1b + (size_t)l * HID;
        const float* b1  = p_b1  + (size_t)l * 2 * HID;
        const float* b2  = p_b2  + (size_t)l * HID;
        const float* l2g = p_l2g + (size_t)l * HID;
        const float* l2b = p_l2b + (size_t)l * HID;

        const uint_t*  kvin  = (const uint_t*)((l & 1) ? kv1 : kv0);
        unsigned char* kvout = (l & 1) ? kv0 : kv1;

        if (l < N_LAYERS - 1) {
            layer_fused<384, false><<<RB, 256, 0, stream>>>(
                buf_h, Wo, W1, W2, wqkv_t + (size_t)(l + 1) * 49152, nullptr,
                bo, l1g, l1b, b1, b2, l2g, l2b, q16, kvin, kvout, d_esrc, d_rows, N);
        } else {
            layer_fused<64, true><<<RB, 256, 0, stream>>>(
                buf_h, Wo, W1, W2, mw0_t, p_mb0,
                bo, l1g, l1b, b1, b2, l2g, l2b, q16, kvin, kvout, d_esrc, d_rows, N);
        }
    }

    // ---- fused readout r1+r2 -> d_out ----
    readout_tail<<<RB, 256, 0, stream>>>(q16, mw1_t, p_mb1, mw2_t, p_mb2, d_out, d_flag, N);
}

// Round 7
// 727.330 us; speedup vs baseline: 1.2467x; 1.2467x over previous
//
#include <hip/hip_runtime.h>
#include <hip/hip_fp16.h>

// ---------------- constants ----------------
#define HID 128
#define N_LAYERS 4
#define IN_DIM 32
#define N_CLASSES 16

typedef _Float16 f16x8 __attribute__((ext_vector_type(8)));
typedef float f32x2 __attribute__((ext_vector_type(2)));
typedef __attribute__((ext_vector_type(4))) float f32x4;
typedef unsigned int uint_t;

#if defined(__has_builtin)
#if __has_builtin(__builtin_amdgcn_cvt_pk_f32_fp8)
#define HAVE_CVT_FP8 1
#endif
#if __has_builtin(__builtin_amdgcn_cvt_pk_fp8_f32)
#define HAVE_ENC_FP8 1
#endif
#endif

__device__ __forceinline__ unsigned short f2bf(float f) {
    unsigned int u = __float_as_uint(f);
    return (unsigned short)((u + 0x7FFFu + ((u >> 16) & 1u)) >> 16);  // RNE
}
__device__ __forceinline__ float2 up16(uint_t u) {
    __half2 h = *(__half2*)&u;
    return __half22float2(h);
}

// ---- fp8 e4m3fn (OCP) encode/decode (manual fallbacks) ----
__device__ __forceinline__ unsigned char f2e4m3(float f) {
    unsigned int u = __float_as_uint(f);
    unsigned char s = (unsigned char)((u >> 24) & 0x80u);
    unsigned int a = u & 0x7FFFFFFFu;
    if (a >= 0x43E00000u) return s | 0x7Eu;
    int exp = (int)(a >> 23) - 127;
    if (exp < -6) {
        int m = (int)rintf(__uint_as_float(a) * 512.f);
        return s | (unsigned char)m;
    }
    unsigned int lsb = (a >> 20) & 1u;
    a += 0x7FFFFu + lsb;
    int e8 = ((int)(a >> 23) - 127) + 7;
    unsigned int m8 = (a >> 20) & 7u;
    return s | (unsigned char)((e8 << 3) | (int)m8);
}
__device__ __forceinline__ float e4m32f(unsigned int b) {
    unsigned int s = (b & 0x80u) << 24;
    unsigned int E = (b >> 3) & 15u, m = b & 7u;
    if (E == 0) {
        float v = (float)m * 0.001953125f;
        return __uint_as_float(__float_as_uint(v) | s);
    }
    return __uint_as_float(s | ((E + 120u) << 23) | (m << 20));
}
__device__ __forceinline__ unsigned char enc8(float v) {
#ifdef HAVE_ENC_FP8
    int r = __builtin_amdgcn_cvt_pk_fp8_f32(v, v, 0, false);
    return (unsigned char)(r & 0xFF);
#else
    return f2e4m3(v);
#endif
}
__device__ __forceinline__ void dec8v(uint_t u, f32x2* o) {  // 4 fp8 -> 2x f32x2
#ifdef HAVE_CVT_FP8
    o[0] = __builtin_amdgcn_cvt_pk_f32_fp8(u, false);
    o[1] = __builtin_amdgcn_cvt_pk_f32_fp8(u, true);
#else
    o[0] = (f32x2){e4m32f(u & 255u), e4m32f((u >> 8) & 255u)};
    o[1] = (f32x2){e4m32f((u >> 16) & 255u), e4m32f(u >> 24)};
#endif
}

// fragment-layout byte offset within a wave's 16x128 A-plane (or a half-tile's 32x128):
// element (row,k): (k>>5)*1024 + ((k>>3)&3)*256 + row*16 + (k&7)*2
__device__ __forceinline__ int frag_off(int row, int c) {
    return ((c >> 5) << 10) + (((c >> 3) & 3) << 8) + (row << 4) + ((c & 7) << 1);
}

// ---------------- dtype detect ----------------
__global__ void detect_kernel(const unsigned int* __restrict__ ln1g, int* __restrict__ flag) {
    if (threadIdx.x == 0 && blockIdx.x == 0)
        *flag = (ln1g[0] == 0x3F800000u) ? 0 : 1;
}

// ---------------- small-param conversion (bf16-or-fp32 -> fp32) ----------------
#define NSM 11
struct SArgs {
    const void* src[NSM];
    float*      dst[NSM];
    int         cnt[NSM];
};

__global__ void conv_kernel(SArgs args, const int* __restrict__ flag) {
    int p = blockIdx.y;
    int n = args.cnt[p];
    int base = (blockIdx.x * 256 + threadIdx.x) * 4;
    if (base >= n) return;
    float* dst = args.dst[p];
    if (*flag) {
        const unsigned short* s = (const unsigned short*)args.src[p];
        #pragma unroll
        for (int j = 0; j < 4; ++j)
            dst[base + j] = __uint_as_float(((unsigned int)s[base + j]) << 16);
    } else {
        const float* s = (const float*)args.src[p];
        *(float4*)&dst[base] = *(const float4*)&s[base];
    }
}

// ---------------- weight conversion: fp16 + layout ----------------
// mode 0: plain transpose dst[m*K+k]
// mode 1: K=128 tiled half-tiles (32 cols x 128 k, fragment-ordered)
// mode 2: K=256 (W2) tiled: htIdx = (k>>7)*4 + (m>>5)
#define NW 27
struct WArgs {
    const void* src[NW];
    int         soff[NW];
    _Float16*   dst[NW];
    int         K[NW];
    int         M[NW];
    int         mode[NW];
};

__global__ void wconv_kernel(WArgs a, const int* __restrict__ flag) {
    int p = blockIdx.y;
    int K = a.K[p], M = a.M[p], mode = a.mode[p];
    int idx = blockIdx.x * 256 + threadIdx.x;
    if (idx >= K * M) return;
    int k = idx / M, m = idx % M;
    float v;
    if (*flag)
        v = __uint_as_float(((unsigned int)((const unsigned short*)a.src[p])[a.soff[p] + idx]) << 16);
    else
        v = ((const float*)a.src[p])[a.soff[p] + idx];
    size_t off;
    if (mode == 0) {
        off = (size_t)m * K + k;
    } else {
        int ht, k2;
        if (mode == 1) { ht = m >> 5; k2 = k; }
        else           { ht = ((k >> 7) << 2) + (m >> 5); k2 = k & 127; }
        // frag = (kk*2 + i2)*64 + quad*16 + lc ; off = ht*4096 + frag*8 + e
        int frag = (((k2 >> 5) * 2 + ((m >> 4) & 1)) << 6) + (((k2 >> 3) & 3) << 4) + (m & 15);
        off = (size_t)ht * 4096 + frag * 8 + (k & 7);
    }
    a.dst[p][off] = (_Float16)v;
}

// ---------------- CSR from sorted edge_dst ----------------
__global__ void csr_kernel(const int* __restrict__ dst, int* __restrict__ row_start,
                           int N, int E) {
    int n = blockIdx.x * 256 + threadIdx.x;
    if (n > N) return;
    int lo = 0, hi = E;
    while (lo < hi) {
        int mid = (lo + hi) >> 1;
        if (dst[mid] < n) lo = mid + 1; else hi = mid;
    }
    row_start[n] = lo;
}

// ---------------- embedding gather (h fp16) ----------------
__global__ void embed_kernel(const int* __restrict__ feat, const float* __restrict__ emb,
                             _Float16* __restrict__ h, int N) {
    int idx = blockIdx.x * 256 + threadIdx.x;   // 8 fp16 per thread
    if (idx >= N * 16) return;
    int n  = idx >> 4;
    int c8 = idx & 15;
    int f = feat[n];
    const float* s = &emb[(size_t)f * HID + c8 * 8];
    float4 a = *(const float4*)s;
    float4 b = *(const float4*)(s + 4);
    f16x8 o;
    o[0] = (_Float16)a.x; o[1] = (_Float16)a.y; o[2] = (_Float16)a.z; o[3] = (_Float16)a.w;
    o[4] = (_Float16)b.x; o[5] = (_Float16)b.y; o[6] = (_Float16)b.z; o[7] = (_Float16)b.w;
    *(f16x8*)&h[(size_t)n * HID + c8 * 8] = o;
}

// ---------------- layer-0 QKV (tiled-B, frag-A) ----------------
__launch_bounds__(256)
__global__ void mfma_gemm_qkv(const _Float16* __restrict__ Ain,
                              const _Float16* __restrict__ Bt,
                              _Float16* __restrict__ q16, unsigned char* __restrict__ kvp8) {
    __shared__ __align__(16) char As[16384];
    __shared__ __align__(16) char Bs[49152];

    const int t    = threadIdx.x;
    const int w    = t >> 6;
    const int l    = t & 63;
    const int quad = l >> 4;
    const int lc   = l & 15;
    const int row0 = blockIdx.x * 64;
    const int mbase = blockIdx.y * 192;

    char* Aw = As + (w << 12);

    // stage A rows w*16..+15, fragment layout (coalesced global read, scatter LDS write)
    #pragma unroll
    for (int i = 0; i < 4; ++i) {
        int idx = i * 64 + l;
        int row = idx >> 4, g = idx & 15;
        uint4 v = *(const uint4*)(Ain + (size_t)(row0 + w * 16 + row) * 128 + g * 8);
        *(uint4*)(Aw + ((g >> 2) << 10) + ((g & 3) << 8) + (row << 4)) = v;
    }
    // stage B: 6 half-tiles linear copy
    {
        const uint4* Bsrc = (const uint4*)(Bt + (size_t)(mbase / 32) * 4096);
        #pragma unroll
        for (int i = 0; i < 12; ++i) {
            int idx = t + i * 256;
            *(uint4*)&Bs[idx * 16] = Bsrc[idx];
        }
    }
    __syncthreads();

    f32x4 acc[12];
    #pragma unroll
    for (int i = 0; i < 12; ++i) acc[i] = (f32x4){0.f, 0.f, 0.f, 0.f};

    #pragma unroll
    for (int kk = 0; kk < 4; ++kk) {
        f16x8 af = *(const f16x8*)(Aw + (kk << 10) + (quad << 8) + (lc << 4));
        #pragma unroll
        for (int i = 0; i < 12; ++i) {
            f16x8 bf = *(const f16x8*)(Bs + (i >> 1) * 8192 +
                                       ((kk * 2 + (i & 1)) << 10) + (quad << 8) + (lc << 4));
            acc[i] = __builtin_amdgcn_mfma_f32_16x16x32_f16(af, bf, acc[i], 0, 0, 0);
        }
    }

    #pragma unroll
    for (int r = 0; r < 4; ++r) {
        int row = row0 + w * 16 + quad * 4 + r;
        #pragma unroll
        for (int i = 0; i < 12; ++i) {
            float v = acc[i][r];
            int gc = mbase + i * 16 + lc;
            if (gc < 128)      q16[(size_t)row * 128 + gc] = (_Float16)v;
            else if (gc < 256) kvp8[(size_t)row * 256 + (gc - 128)] = enc8(v);
            else               kvp8[(size_t)row * 256 + 128 + (gc - 256)] = enc8(v);
        }
    }
}

// ---------------- FULLY-FUSED layer (R5 structure + A-register caching) ----------------
// R5-proven phase pipeline: ISSUE(next half-tile -> buf[bb^1]); MFMA(buf[bb]); epilogue;
// __syncthreads(); bb^=1.  Staged-B via global_load_lds (L2 read once per block, shared
// by 4 waves) — R6 proved direct-global B is 4x worse.  NEW: the A operand is constant
// across each GEMM section, so it is loaded ONCE per section into 16 VGPRs (LDA) instead
// of re-read from LDS every phase — per-phase LDS reads drop 12 -> 8 ds_read_b128.
template<int NEXTM, bool RMODE>
__launch_bounds__(256, 3)
__global__ void layer_fused(_Float16* __restrict__ h,
                            const _Float16* __restrict__ Wo, const _Float16* __restrict__ W1,
                            const _Float16* __restrict__ W2,
                            const _Float16* __restrict__ Wn, const float* __restrict__ bn,
                            const float* __restrict__ bo,  const float* __restrict__ l1g,
                            const float* __restrict__ l1b, const float* __restrict__ b1,
                            const float* __restrict__ b2,  const float* __restrict__ l2g,
                            const float* __restrict__ l2b,
                            _Float16* __restrict__ q16,
                            const uint_t* __restrict__ kvin, unsigned char* __restrict__ kvout,
                            const int* __restrict__ esrc, const int* __restrict__ rows,
                            int N) {
    constexpr int NHT = NEXTM / 32;     // next-proj half-tiles (12 or 2)
    __shared__ __align__(16) char bufA[16384];   // attn-out -> t1 half-plane -> h_new
    __shared__ __align__(16) char bufH[16384];   // h' post-LN1 (frag layout)
    __shared__ __align__(16) char bufB[16384];   // 2 x 8KB weight half-tiles

    const int t = threadIdx.x, w = t >> 6, l = t & 63;
    const int quad = l >> 4, lc = l & 15;
    const int row0 = blockIdx.x * 64;
    char* Aw = bufA + (w << 12);
    char* Hw = bufH + (w << 12);

    auto ISSUE = [&](const _Float16* src, int bsel) {
        char* d = bufB + bsel * 8192 + w * 2048;
        const char* g = (const char*)src + w * 2048 + l * 16;
        __builtin_amdgcn_global_load_lds(
            (const __attribute__((address_space(1))) unsigned int*)g,
            (__attribute__((address_space(3))) unsigned int*)d, 16, 0, 0);
        __builtin_amdgcn_global_load_lds(
            (const __attribute__((address_space(1))) unsigned int*)(g + 1024),
            (__attribute__((address_space(3))) unsigned int*)(d + 1024), 16, 0, 0);
    };
    // load the wave's A fragments (one 16x128 plane) into registers
    auto LDA = [&](const char* Ar, f16x8* afc) {
        #pragma unroll
        for (int kk = 0; kk < 4; ++kk)
            afc[kk] = *(const f16x8*)(Ar + (kk << 10) + (quad << 8) + (lc << 4));
    };
    // 2-tile MFMA: A from register cache, B from staged LDS buffer
    auto MF2 = [&](const f16x8* afc, int bsel, f32x4* ac) {
        const char* B = bufB + bsel * 8192;
        #pragma unroll
        for (int kk = 0; kk < 4; ++kk) {
            #pragma unroll
            for (int i = 0; i < 2; ++i) {
                f16x8 bf = *(const f16x8*)(B + ((kk * 2 + i) << 10) + (quad << 8) + (lc << 4));
                ac[i] = __builtin_amdgcn_mfma_f32_16x16x32_f16(afc[kk], bf, ac[i], 0, 0, 0);
            }
        }
    };

    // ---- prologue: start first weight half-tile immediately ----
    ISSUE(Wo, 0);

    // ---- LN1 residual prefetch (C/D positions) ----
    _Float16 resv[4][8];
    #pragma unroll
    for (int r = 0; r < 4; ++r) {
        int row = row0 + w * 16 + quad * 4 + r;
        #pragma unroll
        for (int j = 0; j < 8; ++j)
            resv[r][j] = h[(size_t)row * 128 + j * 16 + lc];
    }

    // ---- fused edge attention -> Aw (fragment layout), wave-private rows ----
    {
        const int head = l & 7;
        const int rsub = l >> 3;              // 0..7
        #pragma unroll
        for (int task = 0; task < 2; ++task) {
            const int rr   = rsub + task * 8; // row within wave plane, 0..15
            const int node = row0 + w * 16 + rr;
            f16x8 o0, o1;
            #pragma unroll
            for (int j = 0; j < 8; ++j) { o0[j] = (_Float16)0; o1[j] = (_Float16)0; }
            if (node < N) {
                f32x2 qh[8];
                {
                    const uint4* qp = (const uint4*)(q16 + (size_t)node * HID + head * 16);
                    uint4 q0 = qp[0], q1 = qp[1];
                    uint_t qs[8] = {q0.x, q0.y, q0.z, q0.w, q1.x, q1.y, q1.z, q1.w};
                    #pragma unroll
                    for (int i = 0; i < 8; ++i) {
                        float2 f = up16(qs[i]);
                        qh[i] = (f32x2){f.x * 0.25f, f.y * 0.25f};   // fold 1/sqrt(dk)
                    }
                }
                int e0 = rows[node], e1 = rows[node + 1];
                f32x2 wv[8];
                #pragma unroll
                for (int i = 0; i < 8; ++i) wv[i] = (f32x2){0.f, 0.f};
                float z = 0.f;

                uint4 ka = {0,0,0,0}, va = {0,0,0,0}, kc = {0,0,0,0}, vc = {0,0,0,0};
                bool oka = e0 < e1, okc = e0 + 1 < e1;
                if (oka) {
                    int sa = esrc[e0];
                    int sc = okc ? esrc[e0 + 1] : sa;
                    ka = *(const uint4*)(kvin + (size_t)sa * 64 + head * 4);
                    va = *(const uint4*)(kvin + (size_t)sa * 64 + 32 + head * 4);
                    kc = *(const uint4*)(kvin + (size_t)sc * 64 + head * 4);
                    vc = *(const uint4*)(kvin + (size_t)sc * 64 + 32 + head * 4);
                }
                for (int e = e0; e < e1; e += 2) {
                    uint4 cka = ka, cva = va, ckc = kc, cvc = vc;
                    bool coka = oka, cokc = okc;
                    int en = e + 2;
                    oka = en < e1; okc = en + 1 < e1;
                    if (oka) {
                        int sa = esrc[en];
                        int sc = okc ? esrc[en + 1] : sa;
                        ka = *(const uint4*)(kvin + (size_t)sa * 64 + head * 4);
                        va = *(const uint4*)(kvin + (size_t)sa * 64 + 32 + head * 4);
                        kc = *(const uint4*)(kvin + (size_t)sc * 64 + head * 4);
                        vc = *(const uint4*)(kvin + (size_t)sc * 64 + 32 + head * 4);
                    }
                    f32x2 k2a[8], k2c[8];
                    dec8v(cka.x, k2a); dec8v(cka.y, k2a + 2); dec8v(cka.z, k2a + 4); dec8v(cka.w, k2a + 6);
                    dec8v(ckc.x, k2c); dec8v(ckc.y, k2c + 2); dec8v(ckc.z, k2c + 4); dec8v(ckc.w, k2c + 6);
                    f32x2 da2 = (f32x2){0.f, 0.f}, dc2 = (f32x2){0.f, 0.f};
                    #pragma unroll
                    for (int j = 0; j < 8; ++j) { da2 += qh[j] * k2a[j]; dc2 += qh[j] * k2c[j]; }
                    float da = da2.x + da2.y, dc = dc2.x + dc2.y;
                    float sa2 = coka ? __expf(fminf(fmaxf(da, -5.f), 5.f)) : 0.f;
                    float sc2 = cokc ? __expf(fminf(fmaxf(dc, -5.f), 5.f)) : 0.f;

                    f32x2 v2a[8], v2c[8];
                    dec8v(cva.x, v2a); dec8v(cva.y, v2a + 2); dec8v(cva.z, v2a + 4); dec8v(cva.w, v2a + 6);
                    dec8v(cvc.x, v2c); dec8v(cvc.y, v2c + 2); dec8v(cvc.z, v2c + 4); dec8v(cvc.w, v2c + 6);
                    f32x2 pa = (f32x2){sa2, sa2}, pc = (f32x2){sc2, sc2};
                    #pragma unroll
                    for (int j = 0; j < 8; ++j) { wv[j] += pa * v2a[j]; wv[j] += pc * v2c[j]; }
                    z += sa2 + sc2;
                }
                float inv = 1.f / (z + 1e-6f);
                #pragma unroll
                for (int i = 0; i < 4; ++i) {
                    o0[2*i]   = (_Float16)(wv[i].x * inv);
                    o0[2*i+1] = (_Float16)(wv[i].y * inv);
                    o1[2*i]   = (_Float16)(wv[4+i].x * inv);
                    o1[2*i+1] = (_Float16)(wv[4+i].y * inv);
                }
            }
            // write 16 outputs into Aw fragment layout: two aligned 16B spans
            *(f16x8*)(Aw + frag_off(rr, head * 16))     = o0;
            *(f16x8*)(Aw + frag_off(rr, head * 16 + 8)) = o1;
        }
    }

    // cache attn-output A-plane in registers (wave-private, no sync needed)
    f16x8 afA[4];
    LDA(Aw, afA);

    __syncthreads();        // weight buffer 0 ready
    int bb = 0;

    // ---- O-proj: 4 half-tile phases (A from regs) ----
    f32x4 acc[8];
    #pragma unroll
    for (int i = 0; i < 8; ++i) acc[i] = (f32x4){0.f, 0.f, 0.f, 0.f};
    #pragma unroll
    for (int c = 0; c < 4; ++c) {
        ISSUE(c < 3 ? Wo + (c + 1) * 4096 : W1, bb ^ 1);
        MF2(afA, bb, acc + c * 2);
        __syncthreads();
        bb ^= 1;
    }

    // ---- +bo, +res, LN1 -> Hw ----
    {
        float gv[8], bv[8], bb8[8];
        #pragma unroll
        for (int j = 0; j < 8; ++j) {
            int col = j * 16 + lc;
            gv[j] = l1g[col]; bv[j] = l1b[col]; bb8[j] = bo[col];
        }
        #pragma unroll
        for (int r = 0; r < 4; ++r) {
            float v[8];
            float s = 0.f, ss = 0.f;
            #pragma unroll
            for (int j = 0; j < 8; ++j) {
                v[j] = acc[j][r] + bb8[j] + (float)resv[r][j];
                s += v[j]; ss += v[j] * v[j];
            }
            #pragma unroll
            for (int m = 1; m <= 8; m <<= 1) { s += __shfl_xor(s, m); ss += __shfl_xor(ss, m); }
            float mu   = s * (1.f / 128.f);
            float rstd = rsqrtf(ss * (1.f / 128.f) - mu * mu + 1e-5f);
            #pragma unroll
            for (int j = 0; j < 8; ++j) {
                float o = (v[j] - mu) * rstd * gv[j] + bv[j];
                *(_Float16*)(Hw + frag_off(quad * 4 + r, j * 16 + lc)) = (_Float16)o;
            }
        }
    }

    // cache h' A-plane (constant across all FFN1 phases)
    f16x8 afH[4];
    LDA(Hw, afH);

    // ---- FFN1/FFN2 interleaved per K-half ----
    f32x4 acc3[8];
    #pragma unroll
    for (int i = 0; i < 8; ++i) acc3[i] = (f32x4){0.f, 0.f, 0.f, 0.f};
    #pragma unroll
    for (int hh = 0; hh < 2; ++hh) {
        // FFN1: 4 half-tiles -> relu -> Aw (k = j*32 + i2*16 + lc)
        #pragma unroll
        for (int j = 0; j < 4; ++j) {
            ISSUE(j < 3 ? W1 + (hh * 4 + j + 1) * 4096 : W2 + (hh * 4) * 4096, bb ^ 1);
            f32x4 a2[2];
            a2[0] = (f32x4){0.f, 0.f, 0.f, 0.f};
            a2[1] = (f32x4){0.f, 0.f, 0.f, 0.f};
            MF2(afH, bb, a2);
            #pragma unroll
            for (int r = 0; r < 4; ++r) {
                #pragma unroll
                for (int i2 = 0; i2 < 2; ++i2) {
                    float v = a2[i2][r] + b1[(hh * 4 + j) * 32 + i2 * 16 + lc];
                    v = fmaxf(v, 0.f);
                    *(_Float16*)(Aw + frag_off(quad * 4 + r, j * 32 + i2 * 16 + lc)) = (_Float16)v;
                }
            }
            __syncthreads();
            bb ^= 1;
        }
        // cache t1 half-plane (written by this half's FFN1, wave-private)
        f16x8 afT[4];
        LDA(Aw, afT);
        // FFN2: 4 half-tiles, accumulate across halves
        #pragma unroll
        for (int j = 0; j < 4; ++j) {
            const _Float16* nxt;
            if (j < 3)          nxt = W2 + (hh * 4 + j + 1) * 4096;
            else if (hh == 0)   nxt = W1 + 4 * 4096;
            else                nxt = Wn;
            ISSUE(nxt, bb ^ 1);
            MF2(afT, bb, acc3 + j * 2);
            __syncthreads();
            bb ^= 1;
        }
    }

    // ---- +b2, +res(Hw), LN2 -> ov regs (deferred h store) AND Aw ----
    f16x8 ov[4];
    {
        float gv[8], bv[8], bb8[8];
        #pragma unroll
        for (int j = 0; j < 8; ++j) {
            int col = j * 16 + lc;
            gv[j] = l2g[col]; bv[j] = l2b[col]; bb8[j] = b2[col];
        }
        #pragma unroll
        for (int r = 0; r < 4; ++r) {
            float v[8];
            float s = 0.f, ss = 0.f;
            #pragma unroll
            for (int j = 0; j < 8; ++j) {
                float res = (float)*(const _Float16*)(Hw + frag_off(quad * 4 + r, j * 16 + lc));
                v[j] = acc3[j][r] + bb8[j] + res;
                s += v[j]; ss += v[j] * v[j];
            }
            #pragma unroll
            for (int m = 1; m <= 8; m <<= 1) { s += __shfl_xor(s, m); ss += __shfl_xor(ss, m); }
            float mu   = s * (1.f / 128.f);
            float rstd = rsqrtf(ss * (1.f / 128.f) - mu * mu + 1e-5f);
            #pragma unroll
            for (int j = 0; j < 8; ++j) {
                float o = (v[j] - mu) * rstd * gv[j] + bv[j];
                ov[r][j] = (_Float16)o;
                *(_Float16*)(Aw + frag_off(quad * 4 + r, j * 16 + lc)) = (_Float16)o;
            }
        }
    }

    // cache h_new A-plane (constant across all next-proj phases)
    LDA(Aw, afA);

    // ---- next-stage projection, NHT half-tile phases, stores deferred 1 phase ----
    auto storeP = [&](int p, const f32x4* pf) {
        #pragma unroll
        for (int r = 0; r < 4; ++r) {
            int row = row0 + w * 16 + quad * 4 + r;
            #pragma unroll
            for (int i2 = 0; i2 < 2; ++i2) {
                int gc = p * 32 + i2 * 16 + lc;
                float v = pf[i2][r];
                if (RMODE) {
                    v += bn[gc];
                    v = fmaxf(v, 0.f);
                    q16[(size_t)row * 64 + gc] = (_Float16)v;
                } else {
                    if (gc < 128)      q16[(size_t)row * 128 + gc] = (_Float16)v;
                    else if (gc < 256) kvout[(size_t)row * 256 + (gc - 128)] = enc8(v);
                    else               kvout[(size_t)row * 256 + 128 + (gc - 256)] = enc8(v);
                }
            }
        }
    };

    f32x4 pf[2];
    #pragma unroll
    for (int c = 0; c < NHT; ++c) {
        if (c + 1 < NHT) ISSUE(Wn + (c + 1) * 4096, bb ^ 1);
        if (c == 0) {
            // deferred h store (LN2 output) — overlaps this phase's loads
            #pragma unroll
            for (int r = 0; r < 4; ++r) {
                int row = row0 + w * 16 + quad * 4 + r;
                #pragma unroll
                for (int j = 0; j < 8; ++j)
                    h[(size_t)row * 128 + j * 16 + lc] = ov[r][j];
            }
        } else {
            storeP(c - 1, pf);
        }
        f32x4 a4[2];
        a4[0] = (f32x4){0.f, 0.f, 0.f, 0.f};
        a4[1] = (f32x4){0.f, 0.f, 0.f, 0.f};
        MF2(afA, bb, a4);
        if (c + 1 < NHT) __syncthreads();
        bb ^= 1;
        pf[0] = a4[0]; pf[1] = a4[1];
    }
    storeP(NHT - 1, pf);
}

// ---------------- fused readout: r0[N,64] -> relu@mW1 -> @mW2 -> d_out ----------------
__launch_bounds__(256)
__global__ void readout_tail(const _Float16* __restrict__ r0,
                             const _Float16* __restrict__ w1t, const float* __restrict__ b1_,
                             const _Float16* __restrict__ w2t, const float* __restrict__ b2_,
                             void* __restrict__ outp, const int* __restrict__ flag, int N) {
    constexpr int SA = 144;   // 64*2+16
    constexpr int SR = 80;    // 32*2+16
    __shared__ __align__(16) char bufA[64 * SA];
    __shared__ __align__(16) char bufR[64 * SR];

    const int t    = threadIdx.x;
    const int w    = t >> 6;
    const int l    = t & 63;
    const int quad = l >> 4;
    const int lc   = l & 15;
    const int row0 = blockIdx.x * 64;

    #pragma unroll
    for (int i = 0; i < 2; ++i) {
        int idx = t + i * 256;
        int r = idx >> 3, u = idx & 7;
        *(uint4*)&bufA[r * SA + u * 16] = *(const uint4*)(r0 + (size_t)(row0 + r) * 64 + u * 8);
    }
    __syncthreads();

    f32x4 acc[2];
    acc[0] = (f32x4){0.f, 0.f, 0.f, 0.f};
    acc[1] = (f32x4){0.f, 0.f, 0.f, 0.f};
    #pragma unroll
    for (int kk = 0; kk < 2; ++kk) {
        f16x8 af = *(const f16x8*)&bufA[(w * 16 + lc) * SA + kk * 64 + quad * 16];
        #pragma unroll
        for (int i = 0; i < 2; ++i) {
            f16x8 bf = *(const f16x8*)(w1t + (size_t)(i * 16 + lc) * 64 + kk * 32 + quad * 8);
            acc[i] = __builtin_amdgcn_mfma_f32_16x16x32_f16(af, bf, acc[i], 0, 0, 0);
        }
    }
    #pragma unroll
    for (int r = 0; r < 4; ++r) {
        int lrow = (w * 16 + quad * 4 + r) * SR;
        #pragma unroll
        for (int i = 0; i < 2; ++i) {
            float v = acc[i][r] + b1_[i * 16 + lc];
            v = fmaxf(v, 0.f);
            *(_Float16*)&bufR[lrow + (i * 16 + lc) * 2] = (_Float16)v;
        }
    }
    __syncthreads();
    f32x4 a2 = (f32x4){0.f, 0.f, 0.f, 0.f};
    {
        f16x8 af = *(const f16x8*)&bufR[(w * 16 + lc) * SR + quad * 16];
        f16x8 bf = *(const f16x8*)(w2t + (size_t)lc * 32 + quad * 8);
        a2 = __builtin_amdgcn_mfma_f32_16x16x32_f16(af, bf, a2, 0, 0, 0);
    }
    #pragma unroll
    for (int r = 0; r < 4; ++r) {
        int row = row0 + w * 16 + quad * 4 + r;
        if (row < N) {
            float v = a2[r] + b2_[lc];
            size_t o = (size_t)row * 16 + lc;
            if (*flag) ((unsigned short*)outp)[o] = f2bf(v);
            else       ((float*)outp)[o] = v;
        }
    }
}

// ---------------- host launch ----------------
extern "C" void kernel_launch(void* const* d_in, const int* in_sizes, int n_in,
                              void* d_out, int out_size, void* d_ws, size_t ws_size,
                              hipStream_t stream) {
    const int N  = in_sizes[0];
    const int E  = in_sizes[1];
    const int RB = (N + 63) / 64;
    const size_t NP = (size_t)RB * 64;       // padded row count

    const int* d_feat = (const int*)d_in[0];
    const int* d_esrc = (const int*)d_in[1];
    const int* d_edst = (const int*)d_in[2];

    char* base = (char*)d_ws;
    size_t cur = 0;
    auto alloc = [&](size_t bytes) -> char* {
        cur = (cur + 255) & ~(size_t)255;
        char* p = base + cur;
        cur += bytes;
        return p;
    };
    int* d_flag = (int*)alloc(4);
    int* d_rows = (int*)alloc((size_t)(N + 1) * 4);

    // fp32 small params
    float* p_emb = (float*)alloc(IN_DIM * HID * 4);
    float* p_bo  = (float*)alloc(N_LAYERS * HID * 4);
    float* p_l1g = (float*)alloc(N_LAYERS * HID * 4);
    float* p_l1b = (float*)alloc(N_LAYERS * HID * 4);
    float* p_b1  = (float*)alloc(N_LAYERS * 2 * HID * 4);
    float* p_b2  = (float*)alloc(N_LAYERS * HID * 4);
    float* p_l2g = (float*)alloc(N_LAYERS * HID * 4);
    float* p_l2b = (float*)alloc(N_LAYERS * HID * 4);
    float* p_mb0 = (float*)alloc(64 * 4);
    float* p_mb1 = (float*)alloc(32 * 4);
    float* p_mb2 = (float*)alloc(16 * 4);

    // fp16 weights (tiled except mw1/mw2)
    _Float16* wqkv_t = (_Float16*)alloc((size_t)N_LAYERS * 384 * 128 * 2);
    _Float16* wo_t   = (_Float16*)alloc((size_t)N_LAYERS * 128 * 128 * 2);
    _Float16* w1_t   = (_Float16*)alloc((size_t)N_LAYERS * 256 * 128 * 2);
    _Float16* w2_t   = (_Float16*)alloc((size_t)N_LAYERS * 128 * 256 * 2);
    _Float16* mw0_t  = (_Float16*)alloc(64 * 128 * 2);
    _Float16* mw1_t  = (_Float16*)alloc(32 * 64 * 2);
    _Float16* mw2_t  = (_Float16*)alloc(16 * 32 * 2);

    // activations (padded to NP rows)
    _Float16*      buf_h = (_Float16*)alloc(NP * HID * 2);
    _Float16*      q16   = (_Float16*)alloc(NP * HID * 2);   // q / r0
    unsigned char* kv0   = (unsigned char*)alloc(NP * 256);  // fp8 k|v ping
    unsigned char* kv1   = (unsigned char*)alloc(NP * 256);  // fp8 k|v pong

    // ---- 0) dtype detect ----
    detect_kernel<<<1, 64, 0, stream>>>((const unsigned int*)d_in[9], d_flag);

    // ---- 1) small params -> fp32 ----
    {
        SArgs sa;
        const int sidx[NSM] = {3, 8, 9, 10, 12, 14, 15, 16, 18, 20, 22};
        float*    sdst[NSM] = {p_emb, p_bo, p_l1g, p_l1b, p_b1, p_b2, p_l2g, p_l2b, p_mb0, p_mb1, p_mb2};
        const int scnt[NSM] = {IN_DIM*HID, N_LAYERS*HID, N_LAYERS*HID, N_LAYERS*HID,
                               N_LAYERS*2*HID, N_LAYERS*HID, N_LAYERS*HID, N_LAYERS*HID, 64, 32, 16};
        for (int i = 0; i < NSM; ++i) { sa.src[i] = d_in[sidx[i]]; sa.dst[i] = sdst[i]; sa.cnt[i] = scnt[i]; }
        conv_kernel<<<dim3(4, NSM), 256, 0, stream>>>(sa, d_flag);
    }

    // ---- 2) weights -> fp16 (tiled layouts) ----
    {
        WArgs wa;
        int wi = 0;
        auto addw = [&](int inp, int off, int Kd, int Md, _Float16* dst, int mode) {
            wa.src[wi] = d_in[inp]; wa.soff[wi] = off; wa.K[wi] = Kd; wa.M[wi] = Md;
            wa.dst[wi] = dst; wa.mode[wi] = mode; ++wi;
        };
        for (int l = 0; l < N_LAYERS; ++l) {
            addw(4,  l * 16384, 128, 128, wqkv_t + (size_t)l * 49152, 1);
            addw(5,  l * 16384, 128, 128, wqkv_t + (size_t)l * 49152 + 16384, 1);
            addw(6,  l * 16384, 128, 128, wqkv_t + (size_t)l * 49152 + 32768, 1);
            addw(7,  l * 16384, 128, 128, wo_t + (size_t)l * 16384, 1);
            addw(11, l * 32768, 128, 256, w1_t + (size_t)l * 32768, 1);
            addw(13, l * 32768, 256, 128, w2_t + (size_t)l * 32768, 2);
        }
        addw(17, 0, 128, 64, mw0_t, 1);
        addw(19, 0, 64,  32, mw1_t, 0);
        addw(21, 0, 32,  16, mw2_t, 0);
        wconv_kernel<<<dim3(128, NW), 256, 0, stream>>>(wa, d_flag);
    }

    // ---- 3) CSR + embedding ----
    csr_kernel<<<(N + 1 + 255) / 256, 256, 0, stream>>>(d_edst, d_rows, N, E);
    embed_kernel<<<((size_t)N * 16 + 255) / 256, 256, 0, stream>>>(d_feat, p_emb, buf_h, N);

    // ---- layer 0 QKV (tiled-B, 2 col-groups of 192) -> q16 + kv0 ----
    mfma_gemm_qkv<<<dim3(RB, 2), 256, 0, stream>>>(buf_h, wqkv_t, q16, kv0);

    for (int l = 0; l < N_LAYERS; ++l) {
        const _Float16* Wo = wo_t + (size_t)l * 16384;
        const _Float16* W1 = w1_t + (size_t)l * 32768;
        const _Float16* W2 = w2_t + (size_t)l * 32768;
        const float* bo  = p_bo  + (size_t)l * HID;
        const float* l1g = p_l1g + (size_t)l * HID;
        const float* l1b = p_l1b + (size_t)l * HID;
        const float* b1  = p_b1  + (size_t)l * 2 * HID;
        const float* b2  = p_b2  + (size_t)l * HID;
        const float* l2g = p_l2g + (size_t)l * HID;
        const float* l2b = p_l2b + (size_t)l * HID;

        const uint_t*  kvin  = (const uint_t*)((l & 1) ? kv1 : kv0);
        unsigned char* kvout = (l & 1) ? kv0 : kv1;

        if (l < N_LAYERS - 1) {
            layer_fused<384, false><<<RB, 256, 0, stream>>>(
                buf_h, Wo, W1, W2, wqkv_t + (size_t)(l + 1) * 49152, nullptr,
                bo, l1g, l1b, b1, b2, l2g, l2b, q16, kvin, kvout, d_esrc, d_rows, N);
        } else {
            layer_fused<64, true><<<RB, 256, 0, stream>>>(
                buf_h, Wo, W1, W2, mw0_t, p_mb0,
                bo, l1g, l1b, b1, b2, l2g, l2b, q16, kvin, kvout, d_esrc, d_rows, N);
        }
    }

    // ---- fused readout r1+r2 -> d_out ----
    readout_tail<<<RB, 256, 0, stream>>>(q16, mw1_t, p_mb1, mw2_t, p_mb2, d_out, d_flag, N);
}